// Round 7
// baseline (687.708 us; speedup 1.0000x reference)
//
#include <hip/hip_runtime.h>
#include <math.h>

#define N_TOK 131072
#define K_CB  1024
#define D_DIM 64
// packed fixed-point units of 1/2048. 20 units ~= 0.01 >> hi/lo err (~1e-4) + quant (2 units)
#define MARGIN_U 20u

// ws layout: en[1024] f32 @0 ; es frag-major bf16 hi/lo @4096 (256KB) ; fixcnt @266240 ; fixlist @266256
#define WS_EN     0
#define WS_ES     4096
#define WS_CNT    266240
#define WS_LIST   266256

typedef short bf16x8 __attribute__((ext_vector_type(8)));
typedef float f32x4  __attribute__((ext_vector_type(4)));

__device__ __forceinline__ ushort f2bf(float f) {   // RNE fp32->bf16
    uint u = __float_as_uint(f);
    u += 0x7FFFu + ((u >> 16) & 1u);
    return (ushort)(u >> 16);
}
__device__ __forceinline__ float bf2f(ushort h) {
    return __uint_as_float(((uint)h) << 16);
}

// ---- kernel 1: prep (R3-proven vectorized). Thread -> one (cb,ks,quad) 16B hi
// frag + 16B lo frag. es[((cb*4+ks)*64 + quad*16 + jj)] bf16x8; hi ks {0,1}, lo ks+2.
__global__ __launch_bounds__(256) void prep_kernel(
    const float* __restrict__ emb, float* __restrict__ en,
    ushort* __restrict__ es, uint* __restrict__ fixcnt)
{
    const int tid = threadIdx.x;
    const int b   = blockIdx.x;
    if (b == 0 && tid == 0) *fixcnt = 0;

    const int half = tid >> 7;
    const int t    = tid & 127;
    const int cb   = b * 2 + half;
    const int jj   = t & 15;
    const int quad = (t >> 4) & 3;
    const int ks   = (t >> 6) & 1;
    const int code = cb * 16 + jj;

    const float* er = emb + (size_t)code * D_DIM + ks * 32 + quad * 8;
    f32x4 pa = *(const f32x4*)(er);
    f32x4 pb = *(const f32x4*)(er + 4);

    bf16x8 hi, lo;
    #pragma unroll
    for (int j = 0; j < 8; ++j) {
        float f = (j < 4) ? pa[j] : pb[j - 4];
        ushort h = f2bf(f);
        hi[j] = (short)h;
        lo[j] = (short)f2bf(f - bf2f(h));
    }
    bf16x8* out = (bf16x8*)es;
    out[(size_t)(cb * 4 + ks)     * 64 + quad * 16 + jj] = hi;
    out[(size_t)(cb * 4 + ks + 2) * 64 + quad * 16 + jj] = lo;

    if (tid < 32) {
        const int c2 = b * 32 + tid;
        const float* e2 = emb + (size_t)c2 * D_DIM;
        float s = 0.f;
        #pragma unroll
        for (int d = 0; d < D_DIM; ++d) s = fmaf(e2[d], e2[d], s);
        en[c2] = s;
    }
}

// ---- kernel 2: PURE argmin (no output streams -> clean rocprof counters).
// Block = 128 rows, 4 waves: wave (rg,h) = rows rg*64..+64 x chunk-half h (512
// codes). 64 rows/wave (4 row-groups): B-frag loads amortized over 2x the rows
// vs prior (tests the shared-es L2-contention theory). Packed-u32 top-2.
// Result: bk stashed as float into probs[row*K] (writer overwrites all slots).
__global__ __launch_bounds__(256) void vq_argmin(
    const float* __restrict__ x,
    const float* __restrict__ en, const ushort* __restrict__ es,
    float* __restrict__ probs,
    uint* __restrict__ fixcnt, uint* __restrict__ fixlist, uint fixcap)
{
    const int tid  = threadIdx.x;
    const int wave = tid >> 6, lane = tid & 63;
    const int quad = lane >> 4, l15 = lane & 15;
    const int rg = wave >> 1;          // row quarter-pair (64 rows)
    const int h  = wave & 1;           // chunk half (32 chunks = 512 codes)
    const int blockRow = blockIdx.x * 128;
    const int waveRowBase = blockRow + rg * 64;

    __shared__ uint lds_b1[2][128];
    __shared__ uint lds_b2[2][128];

    // A-frags per row-group g (16 rows each): [0]=hi d0..31, [1]=hi d32..63,
    // [2]=lo d0..31, [3]=lo d32..63. A layout (m120): A[m=lane&15][k=quad*8+j].
    bf16x8 af[4][4];
    #pragma unroll
    for (int g = 0; g < 4; ++g) {
        const float* xr = x + (size_t)(waveRowBase + g * 16 + l15) * D_DIM + quad * 8;
        f32x4 p0 = *(const f32x4*)(xr);
        f32x4 p1 = *(const f32x4*)(xr + 4);
        f32x4 p2 = *(const f32x4*)(xr + 32);
        f32x4 p3 = *(const f32x4*)(xr + 36);
        float v0[8], v1[8];
        #pragma unroll
        for (int j = 0; j < 4; ++j) { v0[j] = p0[j]; v0[4 + j] = p1[j]; v1[j] = p2[j]; v1[4 + j] = p3[j]; }
        #pragma unroll
        for (int j = 0; j < 8; ++j) {
            ushort h0 = f2bf(v0[j]);
            af[g][0][j] = (short)h0;
            af[g][2][j] = (short)f2bf(v0[j] - bf2f(h0));
            ushort h1 = f2bf(v1[j]);
            af[g][1][j] = (short)h1;
            af[g][3][j] = (short)f2bf(v1[j] - bf2f(h1));
        }
    }

    uint b1u[16], b2u[16];
    #pragma unroll
    for (int s = 0; s < 16; ++s) { b1u[s] = 0xFFFFFFFFu; b2u[s] = 0xFFFFFFFFu; }

    const bf16x8* __restrict__ esv = (const bf16x8*)es;   // frag-major
    const int fidx = quad * 16 + l15;                     // contiguous 1KB per inst
    const int cb0  = h * 32;

    bf16x8 bc[4]; float enc;
    #pragma unroll
    for (int ks = 0; ks < 4; ++ks) bc[ks] = esv[(size_t)cb0 * 256 + ks * 64 + fidx];
    // enc = 2048*(en+512): en+512-2dot > 0; packed u < 2^31.
    enc = fmaf(en[cb0 * 16 + l15], 2048.f, 1048576.f);

    #pragma unroll 2
    for (int i = 0; i < 32; ++i) {
        const int cb  = cb0 + i;
        const int nbi = cb0 + ((i + 1) & 31);
        bf16x8 bn[4]; float enn;
        #pragma unroll
        for (int ks = 0; ks < 4; ++ks) bn[ks] = esv[(size_t)nbi * 256 + ks * 64 + fidx];
        enn = fmaf(en[nbi * 16 + l15], 2048.f, 1048576.f);

        f32x4 acc[4];
        #pragma unroll
        for (int g = 0; g < 4; ++g) {
            f32x4 a = {0.f, 0.f, 0.f, 0.f};
            // dot = xh*eh + xh*el + xl*eh (xl*el ~1e-4, absorbed by margin)
            a = __builtin_amdgcn_mfma_f32_16x16x32_bf16(af[g][0], bc[0], a, 0, 0, 0);
            a = __builtin_amdgcn_mfma_f32_16x16x32_bf16(af[g][1], bc[1], a, 0, 0, 0);
            a = __builtin_amdgcn_mfma_f32_16x16x32_bf16(af[g][0], bc[2], a, 0, 0, 0);
            a = __builtin_amdgcn_mfma_f32_16x16x32_bf16(af[g][1], bc[3], a, 0, 0, 0);
            a = __builtin_amdgcn_mfma_f32_16x16x32_bf16(af[g][2], bc[0], a, 0, 0, 0);
            a = __builtin_amdgcn_mfma_f32_16x16x32_bf16(af[g][3], bc[1], a, 0, 0, 0);
            acc[g] = a;
        }

        const uint code = (uint)(cb * 16 + l15);
        // C layout (m89): col = lane&15 (this lane's code), row-in-group = quad*4 + r.
        #pragma unroll
        for (int g = 0; g < 4; ++g) {
            #pragma unroll
            for (int r = 0; r < 4; ++r) {
                const int s = g * 4 + r;
                float f = fmaf(-4096.f, acc[g][r], enc);   // 2048*(en+512-2dot) > 0
                uint u = ((uint)f << 10) | code;
                uint lo = min(b1u[s], u), hi = max(b1u[s], u);
                b1u[s] = lo; b2u[s] = min(b2u[s], hi);
            }
        }

        #pragma unroll
        for (int ks = 0; ks < 4; ++ks) bc[ks] = bn[ks];
        enc = enn;
    }

    // butterfly top-2 merge across the 16 lanes holding one row's columns
    #pragma unroll
    for (int s = 0; s < 16; ++s) {
        #pragma unroll
        for (int off = 1; off < 16; off <<= 1) {
            uint o1 = (uint)__shfl_xor((int)b1u[s], off);
            uint o2 = (uint)__shfl_xor((int)b2u[s], off);
            uint lo = min(b1u[s], o1), hi = max(b1u[s], o1);
            b1u[s] = lo;
            b2u[s] = min(min(b2u[s], o2), hi);
        }
    }

    // publish per-half stats: slot s=(g,r) -> in-block row rg*64 + g*16 + quad*4 + r
    if (l15 == 0) {
        #pragma unroll
        for (int s = 0; s < 16; ++s) {
            int idx = rg * 64 + (s >> 2) * 16 + quad * 4 + (s & 3);
            lds_b1[h][idx] = b1u[s];
            lds_b2[h][idx] = b2u[s];
        }
    }
    __syncthreads();

    // merge halves (code in low bits -> first-min tie-break); stash bk in probs
    // slot 0 of the row (writer kernel overwrites every slot afterwards).
    if (tid < 128) {
        uint a1 = lds_b1[0][tid], a2 = lds_b2[0][tid];
        uint c1 = lds_b1[1][tid], c2 = lds_b2[1][tid];
        uint m1 = min(a1, c1);
        uint m2 = min(min(a2, c2), max(a1, c1));
        int  mk = (int)(m1 & 1023u);
        probs[(size_t)(blockRow + tid) * K_CB] = (float)mk;
        if ((m2 >> 10) - (m1 >> 10) <= MARGIN_U) {
            uint idx = atomicAdd(fixcnt, 1u);
            if (idx < fixcap) fixlist[idx] = (uint)(blockRow + tid) | ((uint)mk << 17);
        }
    }
}

// ---- kernel 2b: writer. Block = 64 rows: read stashed bk, gather zq, blast
// one-hot rows with compare-generated values (R0 epilogue pattern, pure stream).
__global__ __launch_bounds__(256) void vq_writer(
    const float* __restrict__ emb,
    float* __restrict__ zq, float* __restrict__ probs)
{
    const int tid  = threadIdx.x;
    const int wave = tid >> 6, lane = tid & 63;
    const int quad = lane >> 4, l15 = lane & 15;
    const int blockRow = blockIdx.x * 64;

    __shared__ int lds_bk[64];
    if (tid < 64)
        lds_bk[tid] = (int)probs[(size_t)(blockRow + tid) * K_CB];
    __syncthreads();

    // zq: wave w rows [w*16, w*16+16): 4 rows/step, quad = row, l15 = col
    #pragma unroll
    for (int mb = 0; mb < 4; ++mb) {
        int rl = wave * 16 + mb * 4 + quad;
        int bk = lds_bk[rl];
        f32x4 v = ((const f32x4*)(emb + (size_t)bk * D_DIM))[l15];
        ((f32x4*)(zq + (size_t)(blockRow + rl) * D_DIM))[l15] = v;
    }

    // one-hot blast: wave w streams its 16 rows x 4KB
    for (int m = 0; m < 16; ++m) {
        int rl = wave * 16 + m;
        int bk = lds_bk[rl];                     // uniform -> LDS broadcast
        float* prow = probs + (size_t)(blockRow + rl) * K_CB;
        #pragma unroll
        for (int s = 0; s < 4; ++s) {
            int c = s * 256 + lane * 4;
            f32x4 v;
            v[0] = (c     == bk) ? 1.f : 0.f;
            v[1] = (c + 1 == bk) ? 1.f : 0.f;
            v[2] = (c + 2 == bk) ? 1.f : 0.f;
            v[3] = (c + 3 == bk) ? 1.f : 0.f;
            *(f32x4*)(prow + c) = v;
        }
    }
}

// ---- kernel 3: exact fp32 re-argmin for flagged rows (wave-per-row).
__global__ __launch_bounds__(256) void vq_fixup(
    const float* __restrict__ x, const float* __restrict__ emb,
    const float* __restrict__ en,
    float* __restrict__ zq, float* __restrict__ probs,
    const uint* __restrict__ fixcnt, const uint* __restrict__ fixlist, uint fixcap)
{
    const int lane = threadIdx.x & 63;
    const int quad = lane >> 4, l15 = lane & 15;
    const uint gwave = (uint)((blockIdx.x * 256 + threadIdx.x) >> 6);
    uint cnt = *fixcnt;
    if (cnt > fixcap) cnt = fixcap;

    for (uint e = gwave; e < cnt; e += 2048u) {
        uint w = fixlist[e];
        int row = (int)(w & 0x1FFFFu);
        int kg  = (int)(w >> 17);

        const f32x4* xr4 = (const f32x4*)(x + (size_t)row * D_DIM) + quad * 4;
        f32x4 xv[4];
        #pragma unroll
        for (int c = 0; c < 4; ++c) xv[c] = xr4[c];
        float xn = 0.f;
        #pragma unroll
        for (int c = 0; c < 4; ++c)
            #pragma unroll
            for (int j = 0; j < 4; ++j) xn = fmaf(xv[c][j], xv[c][j], xn);
        xn += __shfl_xor(xn, 16);
        xn += __shfl_xor(xn, 32);

        float bd = INFINITY; int bk = 0;
        for (int t = 0; t < 64; ++t) {
            int code = t * 16 + l15;                 // ascending per lane
            const f32x4* er4 = (const f32x4*)(emb + (size_t)code * D_DIM) + quad * 4;
            float dot = 0.f;
            #pragma unroll
            for (int c = 0; c < 4; ++c) {
                f32x4 ev = er4[c];
                #pragma unroll
                for (int j = 0; j < 4; ++j) dot = fmaf(xv[c][j], ev[j], dot);
            }
            dot += __shfl_xor(dot, 16);
            dot += __shfl_xor(dot, 32);
            float dist = fmaf(-2.f, dot, xn + en[code]);
            if (dist < bd) { bd = dist; bk = code; }
        }
        #pragma unroll
        for (int off = 1; off < 16; off <<= 1) {
            float od = __shfl_xor(bd, off);
            int   ok = __shfl_xor(bk, off);
            if (od < bd || (od == bd && ok < bk)) { bd = od; bk = ok; }
        }
        if (bk != kg) {
            if (lane == 0) {
                probs[(size_t)row * K_CB + kg] = 0.f;
                probs[(size_t)row * K_CB + bk] = 1.f;
            }
            if (lane < 16)
                ((f32x4*)(zq + (size_t)row * D_DIM))[lane] =
                    ((const f32x4*)(emb + (size_t)bk * D_DIM))[lane];
        }
    }
}

extern "C" void kernel_launch(void* const* d_in, const int* in_sizes, int n_in,
                              void* d_out, int out_size, void* d_ws, size_t ws_size,
                              hipStream_t stream) {
    const float* x   = (const float*)d_in[0];   // [N, D] fp32
    const float* emb = (const float*)d_in[1];   // [K, D] fp32
    float* zq    = (float*)d_out;                              // [N, D]
    float* probs = (float*)d_out + (size_t)N_TOK * D_DIM;      // [N, K]

    char* ws = (char*)d_ws;
    float*  en      = (float*)(ws + WS_EN);
    ushort* es      = (ushort*)(ws + WS_ES);
    uint*   fixcnt  = (uint*)(ws + WS_CNT);
    uint*   fixlist = (uint*)(ws + WS_LIST);
    uint fixcap = (ws_size > WS_LIST + 4) ? (uint)((ws_size - WS_LIST) / 4) : 0u;

    prep_kernel<<<32, 256, 0, stream>>>(emb, en, es, fixcnt);
    vq_argmin<<<N_TOK / 128, 256, 0, stream>>>(x, en, es, probs, fixcnt, fixlist, fixcap);
    vq_writer<<<N_TOK / 64, 256, 0, stream>>>(emb, zq, probs);
    vq_fixup<<<512, 256, 0, stream>>>(x, emb, en, zq, probs, fixcnt, fixlist, fixcap);
}

// Round 8
// 632.993 us; speedup vs baseline: 1.0864x; 1.0864x over previous
//
#include <hip/hip_runtime.h>
#include <math.h>

#define N_TOK 131072
#define K_CB  1024
#define D_DIM 64
// packed fixed-point units of 1/2048. 20 units ~= 0.01 >> hi/lo err (~1e-4) + quant (2 units)
#define MARGIN_U 20u

// ws layout: en[1024] f32 @0 ; es frag-major bf16 hi/lo @4096 (256KB) ; fixcnt @266240 ; fixlist @266256
#define WS_EN     0
#define WS_ES     4096
#define WS_CNT    266240
#define WS_LIST   266256

typedef short bf16x8 __attribute__((ext_vector_type(8)));
typedef float f32x4  __attribute__((ext_vector_type(4)));

__device__ __forceinline__ ushort f2bf(float f) {   // RNE fp32->bf16
    uint u = __float_as_uint(f);
    u += 0x7FFFu + ((u >> 16) & 1u);
    return (ushort)(u >> 16);
}
__device__ __forceinline__ float bf2f(ushort h) {
    return __uint_as_float(((uint)h) << 16);
}
__device__ __forceinline__ f32x4 MF(bf16x8 a, bf16x8 b, f32x4 c) {
    return __builtin_amdgcn_mfma_f32_16x16x32_bf16(a, b, c, 0, 0, 0);
}

// ---- kernel 1: prep (R3-proven vectorized). Thread -> one (cb,ks,quad) 16B hi
// frag + 16B lo frag. es[((cb*4+ks)*64 + quad*16 + jj)] bf16x8; hi ks {0,1}, lo ks+2.
__global__ __launch_bounds__(256) void prep_kernel(
    const float* __restrict__ emb, float* __restrict__ en,
    ushort* __restrict__ es, uint* __restrict__ fixcnt)
{
    const int tid = threadIdx.x;
    const int b   = blockIdx.x;
    if (b == 0 && tid == 0) *fixcnt = 0;

    const int half = tid >> 7;
    const int t    = tid & 127;
    const int cb   = b * 2 + half;
    const int jj   = t & 15;
    const int quad = (t >> 4) & 3;
    const int ks   = (t >> 6) & 1;
    const int code = cb * 16 + jj;

    const float* er = emb + (size_t)code * D_DIM + ks * 32 + quad * 8;
    f32x4 pa = *(const f32x4*)(er);
    f32x4 pb = *(const f32x4*)(er + 4);

    bf16x8 hi, lo;
    #pragma unroll
    for (int j = 0; j < 8; ++j) {
        float f = (j < 4) ? pa[j] : pb[j - 4];
        ushort h = f2bf(f);
        hi[j] = (short)h;
        lo[j] = (short)f2bf(f - bf2f(h));
    }
    bf16x8* out = (bf16x8*)es;
    out[(size_t)(cb * 4 + ks)     * 64 + quad * 16 + jj] = hi;
    out[(size_t)(cb * 4 + ks + 2) * 64 + quad * 16 + jj] = lo;

    if (tid < 32) {
        const int c2 = b * 32 + tid;
        const float* e2 = emb + (size_t)c2 * D_DIM;
        float s = 0.f;
        #pragma unroll
        for (int d = 0; d < D_DIM; ++d) s = fmaf(e2[d], e2[d], s);
        en[c2] = s;
    }
}

// ---- kernel 2: fused argmin + one-hot. Block = 64 rows, 4 waves: wave (rg,h) =
// rows rg*32..+32 x chunk-half h (512 codes). K-loop is an EXPLICIT 2-BUFFER
// SOFTWARE PIPELINE with no register copies: unrolled x2, named buffers A/B
// alternate; prefetch for chunk i+2 issues right after the MFMAs consuming A
// (latency hides under min-update VALU + the B-chunk compute). This removes the
// per-iteration vmcnt(0) drain the bc=bn copies forced (the ~2000cyc/iter =
// 5 serialized L2-latency loads pathology). Packed-u32 top-2, R0 compare-blast.
__global__ __launch_bounds__(256, 3) void vq_onehot(
    const float* __restrict__ x, const float* __restrict__ emb,
    const float* __restrict__ en, const ushort* __restrict__ es,
    float* __restrict__ zq, float* __restrict__ probs,
    uint* __restrict__ fixcnt, uint* __restrict__ fixlist, uint fixcap)
{
    const int tid  = threadIdx.x;
    const int wave = tid >> 6, lane = tid & 63;
    const int quad = lane >> 4, l15 = lane & 15;
    const int rg = wave >> 1;          // row half (32 rows)
    const int h  = wave & 1;           // chunk half (32 chunks = 512 codes)
    const int blockRow = blockIdx.x * 64;
    const int waveRowBase = blockRow + rg * 32;

    __shared__ uint lds_b1[2][64];
    __shared__ uint lds_b2[2][64];
    __shared__ int  lds_bk[64];

    // A-frags per row-group g: [0]=hi d0..31, [1]=hi d32..63, [2]=lo d0..31, [3]=lo d32..63.
    // A layout (m120): A[m=lane&15][k=quad*8+j].
    bf16x8 af[2][4];
    #pragma unroll
    for (int g = 0; g < 2; ++g) {
        const float* xr = x + (size_t)(waveRowBase + g * 16 + l15) * D_DIM + quad * 8;
        f32x4 p0 = *(const f32x4*)(xr);
        f32x4 p1 = *(const f32x4*)(xr + 4);
        f32x4 p2 = *(const f32x4*)(xr + 32);
        f32x4 p3 = *(const f32x4*)(xr + 36);
        float v0[8], v1[8];
        #pragma unroll
        for (int j = 0; j < 4; ++j) { v0[j] = p0[j]; v0[4 + j] = p1[j]; v1[j] = p2[j]; v1[4 + j] = p3[j]; }
        #pragma unroll
        for (int j = 0; j < 8; ++j) {
            ushort h0 = f2bf(v0[j]);
            af[g][0][j] = (short)h0;
            af[g][2][j] = (short)f2bf(v0[j] - bf2f(h0));
            ushort h1 = f2bf(v1[j]);
            af[g][1][j] = (short)h1;
            af[g][3][j] = (short)f2bf(v1[j] - bf2f(h1));
        }
    }

    uint b1u[8], b2u[8];
    #pragma unroll
    for (int s = 0; s < 8; ++s) { b1u[s] = 0xFFFFFFFFu; b2u[s] = 0xFFFFFFFFu; }

    const bf16x8* __restrict__ esv = (const bf16x8*)es;   // frag-major
    const int fidx = quad * 16 + l15;                     // contiguous 1KB per inst
    const int cb0  = h * 32;

    // two named buffer sets (no arrays -> no runtime indexing, no copies)
    bf16x8 A0, A1, A2, A3, B0, B1, B2, B3;
    float enA, enB;
    {
        size_t ba = (size_t)cb0 * 256 + fidx;
        A0 = esv[ba]; A1 = esv[ba + 64]; A2 = esv[ba + 128]; A3 = esv[ba + 192];
        enA = fmaf(en[cb0 * 16 + l15], 2048.f, 1048576.f);   // 2048*(en+512)
        size_t bb = (size_t)(cb0 + 1) * 256 + fidx;
        B0 = esv[bb]; B1 = esv[bb + 64]; B2 = esv[bb + 128]; B3 = esv[bb + 192];
        enB = fmaf(en[(cb0 + 1) * 16 + l15], 2048.f, 1048576.f);
    }

    #define MINUPD(ACC0, ACC1, ECV, CODE) do {                                   \
        const uint code_ = (CODE);                                               \
        _Pragma("unroll")                                                        \
        for (int r = 0; r < 4; ++r) {                                            \
            {                                                                    \
                float f_ = fmaf(-4096.f, (ACC0)[r], (ECV));                      \
                uint u_ = ((uint)f_ << 10) | code_;                              \
                uint lo_ = min(b1u[r], u_), hi_ = max(b1u[r], u_);               \
                b1u[r] = lo_; b2u[r] = min(b2u[r], hi_);                         \
            }                                                                    \
            {                                                                    \
                float f_ = fmaf(-4096.f, (ACC1)[r], (ECV));                      \
                uint u_ = ((uint)f_ << 10) | code_;                              \
                uint lo_ = min(b1u[4 + r], u_), hi_ = max(b1u[4 + r], u_);       \
                b1u[4 + r] = lo_; b2u[4 + r] = min(b2u[4 + r], hi_);             \
            }                                                                    \
        }                                                                        \
    } while (0)

    for (int i = 0; i < 32; i += 2) {
        {   // chunk i from A; prefetch i+2 into A after consumption
            f32x4 acc0 = {0.f, 0.f, 0.f, 0.f};
            f32x4 acc1 = {0.f, 0.f, 0.f, 0.f};
            // dot = xh*eh + xh*el + xl*eh  (xl*el ~1e-4, absorbed by margin)
            acc0 = MF(af[0][0], A0, acc0); acc0 = MF(af[0][1], A1, acc0);
            acc0 = MF(af[0][0], A2, acc0); acc0 = MF(af[0][1], A3, acc0);
            acc0 = MF(af[0][2], A0, acc0); acc0 = MF(af[0][3], A1, acc0);
            acc1 = MF(af[1][0], A0, acc1); acc1 = MF(af[1][1], A1, acc1);
            acc1 = MF(af[1][0], A2, acc1); acc1 = MF(af[1][1], A3, acc1);
            acc1 = MF(af[1][2], A0, acc1); acc1 = MF(af[1][3], A1, acc1);
            const float ec = enA;
            const uint  cd = (uint)((cb0 + i) * 16 + l15);
            {   // prefetch (A regs free after the MFMAs above)
                int nc = cb0 + ((i + 2) & 31);
                size_t bn = (size_t)nc * 256 + fidx;
                A0 = esv[bn]; A1 = esv[bn + 64]; A2 = esv[bn + 128]; A3 = esv[bn + 192];
                enA = fmaf(en[nc * 16 + l15], 2048.f, 1048576.f);
            }
            MINUPD(acc0, acc1, ec, cd);
        }
        {   // chunk i+1 from B; prefetch i+3 into B
            f32x4 acc0 = {0.f, 0.f, 0.f, 0.f};
            f32x4 acc1 = {0.f, 0.f, 0.f, 0.f};
            acc0 = MF(af[0][0], B0, acc0); acc0 = MF(af[0][1], B1, acc0);
            acc0 = MF(af[0][0], B2, acc0); acc0 = MF(af[0][1], B3, acc0);
            acc0 = MF(af[0][2], B0, acc0); acc0 = MF(af[0][3], B1, acc0);
            acc1 = MF(af[1][0], B0, acc1); acc1 = MF(af[1][1], B1, acc1);
            acc1 = MF(af[1][0], B2, acc1); acc1 = MF(af[1][1], B3, acc1);
            acc1 = MF(af[1][2], B0, acc1); acc1 = MF(af[1][3], B1, acc1);
            const float ec = enB;
            const uint  cd = (uint)((cb0 + i + 1) * 16 + l15);
            {
                int nc = cb0 + ((i + 3) & 31);
                size_t bn = (size_t)nc * 256 + fidx;
                B0 = esv[bn]; B1 = esv[bn + 64]; B2 = esv[bn + 128]; B3 = esv[bn + 192];
                enB = fmaf(en[nc * 16 + l15], 2048.f, 1048576.f);
            }
            MINUPD(acc0, acc1, ec, cd);
        }
    }
    #undef MINUPD

    // butterfly top-2 merge across the 16 lanes holding one row's columns
    #pragma unroll
    for (int s = 0; s < 8; ++s) {
        #pragma unroll
        for (int off = 1; off < 16; off <<= 1) {
            uint o1 = (uint)__shfl_xor((int)b1u[s], off);
            uint o2 = (uint)__shfl_xor((int)b2u[s], off);
            uint lo = min(b1u[s], o1), hi = max(b1u[s], o1);
            b1u[s] = lo;
            b2u[s] = min(min(b2u[s], o2), hi);
        }
    }

    // publish per-half stats
    if (l15 == 0) {
        #pragma unroll
        for (int s = 0; s < 8; ++s) {
            int idx = rg * 32 + (s >> 2) * 16 + quad * 4 + (s & 3);  // 0..63 in-block row
            lds_b1[h][idx] = b1u[s];
            lds_b2[h][idx] = b2u[s];
        }
    }
    __syncthreads();

    // merge chunk halves (code in low bits -> global first-min tie-break)
    if (tid < 64) {
        uint a1 = lds_b1[0][tid], a2 = lds_b2[0][tid];
        uint c1 = lds_b1[1][tid], c2 = lds_b2[1][tid];
        uint m1 = min(a1, c1);
        uint m2 = min(min(a2, c2), max(a1, c1));
        int  mk = (int)(m1 & 1023u);
        lds_bk[tid] = mk;
        if ((m2 >> 10) - (m1 >> 10) <= MARGIN_U) {
            uint idx = atomicAdd(fixcnt, 1u);
            if (idx < fixcap) fixlist[idx] = (uint)(blockRow + tid) | ((uint)mk << 17);
        }
    }
    __syncthreads();

    // zq: wave w writes rows [w*16, w*16+16): 4 rows/step, quad = row, l15 = col
    #pragma unroll
    for (int mb = 0; mb < 4; ++mb) {
        int rl = wave * 16 + mb * 4 + quad;
        int bk = lds_bk[rl];
        f32x4 v = ((const f32x4*)(emb + (size_t)bk * D_DIM))[l15];
        ((f32x4*)(zq + (size_t)(blockRow + rl) * D_DIM))[l15] = v;
    }

    // one-hot blast: wave w streams its 16 rows x 4KB, compare-generated values
    for (int m = 0; m < 16; ++m) {
        int rl = wave * 16 + m;
        int bk = lds_bk[rl];                     // uniform -> LDS broadcast
        float* prow = probs + (size_t)(blockRow + rl) * K_CB;
        #pragma unroll
        for (int s = 0; s < 4; ++s) {
            int c = s * 256 + lane * 4;
            f32x4 v;
            v[0] = (c     == bk) ? 1.f : 0.f;
            v[1] = (c + 1 == bk) ? 1.f : 0.f;
            v[2] = (c + 2 == bk) ? 1.f : 0.f;
            v[3] = (c + 3 == bk) ? 1.f : 0.f;
            *(f32x4*)(prow + c) = v;
        }
    }
}

// ---- kernel 3: exact fp32 re-argmin for flagged rows (wave-per-row).
__global__ __launch_bounds__(256) void vq_fixup(
    const float* __restrict__ x, const float* __restrict__ emb,
    const float* __restrict__ en,
    float* __restrict__ zq, float* __restrict__ probs,
    const uint* __restrict__ fixcnt, const uint* __restrict__ fixlist, uint fixcap)
{
    const int lane = threadIdx.x & 63;
    const int quad = lane >> 4, l15 = lane & 15;
    const uint gwave = (uint)((blockIdx.x * 256 + threadIdx.x) >> 6);
    uint cnt = *fixcnt;
    if (cnt > fixcap) cnt = fixcap;

    for (uint e = gwave; e < cnt; e += 1024u) {
        uint w = fixlist[e];
        int row = (int)(w & 0x1FFFFu);
        int kg  = (int)(w >> 17);

        const f32x4* xr4 = (const f32x4*)(x + (size_t)row * D_DIM) + quad * 4;
        f32x4 xv[4];
        #pragma unroll
        for (int c = 0; c < 4; ++c) xv[c] = xr4[c];
        float xn = 0.f;
        #pragma unroll
        for (int c = 0; c < 4; ++c)
            #pragma unroll
            for (int j = 0; j < 4; ++j) xn = fmaf(xv[c][j], xv[c][j], xn);
        xn += __shfl_xor(xn, 16);
        xn += __shfl_xor(xn, 32);

        float bd = INFINITY; int bk = 0;
        for (int t = 0; t < 64; ++t) {
            int code = t * 16 + l15;                 // ascending per lane
            const f32x4* er4 = (const f32x4*)(emb + (size_t)code * D_DIM) + quad * 4;
            float dot = 0.f;
            #pragma unroll
            for (int c = 0; c < 4; ++c) {
                f32x4 ev = er4[c];
                #pragma unroll
                for (int j = 0; j < 4; ++j) dot = fmaf(xv[c][j], ev[j], dot);
            }
            dot += __shfl_xor(dot, 16);
            dot += __shfl_xor(dot, 32);
            float dist = fmaf(-2.f, dot, xn + en[code]);
            if (dist < bd) { bd = dist; bk = code; }
        }
        #pragma unroll
        for (int off = 1; off < 16; off <<= 1) {
            float od = __shfl_xor(bd, off);
            int   ok = __shfl_xor(bk, off);
            if (od < bd || (od == bd && ok < bk)) { bd = od; bk = ok; }
        }
        if (bk != kg) {
            if (lane == 0) {
                probs[(size_t)row * K_CB + kg] = 0.f;
                probs[(size_t)row * K_CB + bk] = 1.f;
            }
            if (lane < 16)
                ((f32x4*)(zq + (size_t)row * D_DIM))[lane] =
                    ((const f32x4*)(emb + (size_t)bk * D_DIM))[lane];
        }
    }
}

extern "C" void kernel_launch(void* const* d_in, const int* in_sizes, int n_in,
                              void* d_out, int out_size, void* d_ws, size_t ws_size,
                              hipStream_t stream) {
    const float* x   = (const float*)d_in[0];   // [N, D] fp32
    const float* emb = (const float*)d_in[1];   // [K, D] fp32
    float* zq    = (float*)d_out;                              // [N, D]
    float* probs = (float*)d_out + (size_t)N_TOK * D_DIM;      // [N, K]

    char* ws = (char*)d_ws;
    float*  en      = (float*)(ws + WS_EN);
    ushort* es      = (ushort*)(ws + WS_ES);
    uint*   fixcnt  = (uint*)(ws + WS_CNT);
    uint*   fixlist = (uint*)(ws + WS_LIST);
    uint fixcap = (ws_size > WS_LIST + 4) ? (uint)((ws_size - WS_LIST) / 4) : 0u;

    prep_kernel<<<32, 256, 0, stream>>>(emb, en, es, fixcnt);
    vq_onehot<<<N_TOK / 64, 256, 0, stream>>>(x, emb, en, es, zq, probs, fixcnt, fixlist, fixcap);
    vq_fixup<<<256, 256, 0, stream>>>(x, emb, en, zq, probs, fixcnt, fixlist, fixcap);
}